// Round 1
// baseline (8648.335 us; speedup 1.0000x reference)
//
#include <hip/hip_runtime.h>
#include <cmath>

#define HID 150
#define NN 100000
#define NE 1600000
#define NL 5
#define MT 8          // nodes per block in gemm/gru kernels
#define G3 (3*HID)    // 450

// ---------------- transpose weights: wt[k*450 + j] = w[j*150 + k] ----------------
__global__ void transpose_w(const float* __restrict__ w, float* __restrict__ wt) {
    int idx = blockIdx.x * blockDim.x + threadIdx.x;  // over 450*150
    if (idx >= G3 * HID) return;
    int j = idx / HID;
    int k = idx - j * HID;
    wt[k * G3 + j] = w[idx];
}

// ---------------- m = h @ W  (W row-major [150,150]) ----------------
__global__ void gemm_m(const float* __restrict__ h, const float* __restrict__ W,
                       float* __restrict__ m) {
    __shared__ float hs[MT][HID];
    int n0 = blockIdx.x * MT;
    for (int i = threadIdx.x; i < MT * HID; i += blockDim.x) {
        int ni = i / HID;
        int k  = i - ni * HID;
        hs[ni][k] = h[(size_t)(n0 + ni) * HID + k];
    }
    __syncthreads();
    int f = threadIdx.x;
    if (f >= HID) return;
    float acc[MT];
#pragma unroll
    for (int i = 0; i < MT; ++i) acc[i] = 0.f;
    for (int k = 0; k < HID; ++k) {
        float w = W[k * HID + f];
#pragma unroll
        for (int i = 0; i < MT; ++i) acc[i] += hs[i][k] * w;
    }
#pragma unroll
    for (int i = 0; i < MT; ++i) m[(size_t)(n0 + i) * HID + f] = acc[i];
}

// ---------------- scatter: aggr[dst] += m[src] over edges ----------------
__global__ void scatter_add(const float* __restrict__ m, const int* __restrict__ ei,
                            float* __restrict__ aggr) {
    int e = blockIdx.x;
    int f = threadIdx.x;
    int src = ei[e];
    int dst = ei[NE + e];
    if (f < HID) {
        atomicAdd(&aggr[(size_t)dst * HID + f], m[(size_t)src * HID + f]);
    }
}

// ---------------- fused GRU cell, 8 nodes per block ----------------
__global__ void gru_cell(const float* __restrict__ aggr, const float* __restrict__ h_in,
                         const float* __restrict__ wiht, const float* __restrict__ whht,
                         const float* __restrict__ bih, const float* __restrict__ bhh,
                         float* __restrict__ h_out) {
    __shared__ float as[MT][HID];
    __shared__ float hs[MT][HID];
    int n0 = blockIdx.x * MT;
    for (int i = threadIdx.x; i < MT * HID; i += blockDim.x) {
        int ni = i / HID;
        int k  = i - ni * HID;
        as[ni][k] = aggr[(size_t)(n0 + ni) * HID + k];
        hs[ni][k] = h_in[(size_t)(n0 + ni) * HID + k];
    }
    __syncthreads();
    int f = threadIdx.x;
    if (f >= HID) return;

    float ir[MT], iz[MT], inn[MT], hr[MT], hz[MT], hn[MT];
    float bir = bih[f], biz = bih[HID + f], bin = bih[2 * HID + f];
    float bhr = bhh[f], bhz = bhh[HID + f], bhn = bhh[2 * HID + f];
#pragma unroll
    for (int i = 0; i < MT; ++i) {
        ir[i] = bir; iz[i] = biz; inn[i] = bin;
        hr[i] = bhr; hz[i] = bhz; hn[i] = bhn;
    }
    for (int k = 0; k < HID; ++k) {
        const float* wi = wiht + (size_t)k * G3;
        const float* wh = whht + (size_t)k * G3;
        float wir = wi[f], wiz = wi[HID + f], win = wi[2 * HID + f];
        float whr = wh[f], whz = wh[HID + f], whn = wh[2 * HID + f];
#pragma unroll
        for (int i = 0; i < MT; ++i) {
            float a = as[i][k], hv = hs[i][k];
            ir[i] += a * wir;  iz[i] += a * wiz;  inn[i] += a * win;
            hr[i] += hv * whr; hz[i] += hv * whz; hn[i] += hv * whn;
        }
    }
#pragma unroll
    for (int i = 0; i < MT; ++i) {
        float r = 1.f / (1.f + __expf(-(ir[i] + hr[i])));
        float z = 1.f / (1.f + __expf(-(iz[i] + hz[i])));
        float n = tanhf(inn[i] + r * hn[i]);
        h_out[(size_t)(n0 + i) * HID + f] = (1.f - z) * n + z * hs[i][f];
    }
}

extern "C" void kernel_launch(void* const* d_in, const int* in_sizes, int n_in,
                              void* d_out, int out_size, void* d_ws, size_t ws_size,
                              hipStream_t stream) {
    const float* x      = (const float*)d_in[0];
    const float* weight = (const float*)d_in[1];   // [5,150,150]
    const float* w_ih   = (const float*)d_in[2];   // [450,150]
    const float* w_hh   = (const float*)d_in[3];   // [450,150]
    const float* b_ih   = (const float*)d_in[4];   // [450]
    const float* b_hh   = (const float*)d_in[5];   // [450]
    const int*   ei     = (const int*)d_in[6];     // [2,NE]
    float* h = (float*)d_out;                      // [NN,150]

    char* ws = (char*)d_ws;
    const size_t NHB = (size_t)NN * HID * sizeof(float);   // 60 MB
    float* m    = (float*)ws;
    float* aggr = (float*)(ws + NHB);
    float* wiht = (float*)(ws + 2 * NHB);
    float* whht = wiht + (size_t)G3 * HID;

    int tb = (G3 * HID + 255) / 256;
    transpose_w<<<tb, 256, 0, stream>>>(w_ih, wiht);
    transpose_w<<<tb, 256, 0, stream>>>(w_hh, whht);

    for (int l = 0; l < NL; ++l) {
        const float* hin = (l == 0) ? x : h;
        gemm_m<<<NN / MT, 192, 0, stream>>>(hin, weight + (size_t)l * HID * HID, m);
        hipMemsetAsync(aggr, 0, NHB, stream);
        scatter_add<<<NE, 192, 0, stream>>>(m, ei, aggr);
        gru_cell<<<NN / MT, 192, 0, stream>>>(aggr, hin, wiht, whht, b_ih, b_hh, h);
    }
}

// Round 2
// 4243.542 us; speedup vs baseline: 2.0380x; 2.0380x over previous
//
#include <hip/hip_runtime.h>
#include <cmath>

#define HID 150
#define NN 100000
#define NE 1600000
#define NL 5
#define MT 8          // nodes per block in gru kernel
#define G3 (3*HID)    // 450
#define SCAN_T 1024
#define CHUNK 98      // ceil(NN / SCAN_T)

// ---------------- transpose weights: wt[k*450 + j] = w[j*150 + k] ----------------
__global__ void transpose_w(const float* __restrict__ w, float* __restrict__ wt) {
    int idx = blockIdx.x * blockDim.x + threadIdx.x;  // over 450*150
    if (idx >= G3 * HID) return;
    int j = idx / HID;
    int k = idx - j * HID;
    wt[k * G3 + j] = w[idx];
}

// ---------------- fusedT[l][k][j] = (W_l @ w_ih^T)[k][j] = sum_t W_l[k][t]*w_ih[j][t] ----------------
__global__ void build_fused(const float* __restrict__ W, const float* __restrict__ wiht,
                            float* __restrict__ fusedT) {
    int idx = blockIdx.x * blockDim.x + threadIdx.x;
    if (idx >= NL * HID * G3) return;
    int j = idx % G3;
    int rest = idx / G3;
    int k = rest % HID;
    int l = rest / HID;
    const float* Wl = W + (size_t)l * HID * HID + (size_t)k * HID;
    float acc = 0.f;
    for (int t = 0; t < HID; ++t) acc += Wl[t] * wiht[t * G3 + j];
    fusedT[idx] = acc;
}

// ---------------- CSR build: histogram, scan, fill ----------------
__global__ void hist_deg(const int* __restrict__ ei, int* __restrict__ deg) {
    int e = blockIdx.x * blockDim.x + threadIdx.x;
    if (e < NE) atomicAdd(&deg[ei[NE + e]], 1);
}

__global__ void scan_offsets(const int* __restrict__ deg, int* __restrict__ off,
                             int* __restrict__ pos) {
    __shared__ int s[SCAN_T];
    int t = threadIdx.x;
    int lo = t * CHUNK;
    int hi = lo + CHUNK; if (hi > NN) hi = NN;
    int sum = 0;
    for (int i = lo; i < hi; ++i) sum += deg[i];
    s[t] = sum;
    __syncthreads();
    for (int d = 1; d < SCAN_T; d <<= 1) {
        int v = (t >= d) ? s[t - d] : 0;
        __syncthreads();
        s[t] += v;
        __syncthreads();
    }
    int base = s[t] - sum;   // exclusive prefix
    for (int i = lo; i < hi; ++i) {
        off[i] = base; pos[i] = base;
        base += deg[i];
    }
    if (t == 0) off[NN] = s[SCAN_T - 1];
}

__global__ void fill_csr(const int* __restrict__ ei, int* __restrict__ pos,
                         int* __restrict__ csr) {
    int e = blockIdx.x * blockDim.x + threadIdx.x;
    if (e < NE) {
        int p = atomicAdd(&pos[ei[NE + e]], 1);
        csr[p] = ei[e];
    }
}

// ---------------- aggregate: one wave per node, sum h[src] rows (no atomics) ----------------
__global__ void aggregate(const float* __restrict__ h, const int* __restrict__ off,
                          const int* __restrict__ csr, float* __restrict__ out) {
    int wave = (blockIdx.x * blockDim.x + threadIdx.x) >> 6;
    int lane = threadIdx.x & 63;
    if (wave >= NN) return;
    int e0 = off[wave], e1 = off[wave + 1];
    float a0 = 0.f, a1 = 0.f, a2 = 0.f;
    bool has2 = (lane + 128) < HID;   // lanes 0..21
    for (int e = e0; e < e1; ++e) {
        const float* row = h + (size_t)csr[e] * HID;
        a0 += row[lane];
        a1 += row[lane + 64];
        if (has2) a2 += row[lane + 128];
    }
    float* o = out + (size_t)wave * HID;
    o[lane] = a0;
    o[lane + 64] = a1;
    if (has2) o[lane + 128] = a2;
}

// ---------------- fused GRU cell, 8 nodes per block ----------------
// gi = aggrH @ fusedT_l + b_ih ; gh = h @ whht + b_hh
__global__ void gru_cell(const float* __restrict__ aggrH, const float* __restrict__ h_in,
                         const float* __restrict__ fusedTl, const float* __restrict__ whht,
                         const float* __restrict__ bih, const float* __restrict__ bhh,
                         float* __restrict__ h_out) {
    __shared__ float as[MT][HID];
    __shared__ float hs[MT][HID];
    int n0 = blockIdx.x * MT;
    for (int i = threadIdx.x; i < MT * HID; i += blockDim.x) {
        int ni = i / HID;
        int k  = i - ni * HID;
        as[ni][k] = aggrH[(size_t)(n0 + ni) * HID + k];
        hs[ni][k] = h_in[(size_t)(n0 + ni) * HID + k];
    }
    __syncthreads();
    int f = threadIdx.x;
    if (f >= HID) return;

    float ir[MT], iz[MT], inn[MT], hr[MT], hz[MT], hn[MT];
    float bir = bih[f], biz = bih[HID + f], bin = bih[2 * HID + f];
    float bhr = bhh[f], bhz = bhh[HID + f], bhn = bhh[2 * HID + f];
#pragma unroll
    for (int i = 0; i < MT; ++i) {
        ir[i] = bir; iz[i] = biz; inn[i] = bin;
        hr[i] = bhr; hz[i] = bhz; hn[i] = bhn;
    }
    for (int k = 0; k < HID; ++k) {
        const float* wi = fusedTl + (size_t)k * G3;
        const float* wh = whht + (size_t)k * G3;
        float wir = wi[f], wiz = wi[HID + f], win = wi[2 * HID + f];
        float whr = wh[f], whz = wh[HID + f], whn = wh[2 * HID + f];
#pragma unroll
        for (int i = 0; i < MT; ++i) {
            float a = as[i][k], hv = hs[i][k];
            ir[i] += a * wir;  iz[i] += a * wiz;  inn[i] += a * win;
            hr[i] += hv * whr; hz[i] += hv * whz; hn[i] += hv * whn;
        }
    }
#pragma unroll
    for (int i = 0; i < MT; ++i) {
        float r = 1.f / (1.f + __expf(-(ir[i] + hr[i])));
        float z = 1.f / (1.f + __expf(-(iz[i] + hz[i])));
        float n = tanhf(inn[i] + r * hn[i]);
        h_out[(size_t)(n0 + i) * HID + f] = (1.f - z) * n + z * hs[i][f];
    }
}

extern "C" void kernel_launch(void* const* d_in, const int* in_sizes, int n_in,
                              void* d_out, int out_size, void* d_ws, size_t ws_size,
                              hipStream_t stream) {
    const float* x      = (const float*)d_in[0];
    const float* weight = (const float*)d_in[1];   // [5,150,150]
    const float* w_ih   = (const float*)d_in[2];   // [450,150]
    const float* w_hh   = (const float*)d_in[3];   // [450,150]
    const float* b_ih   = (const float*)d_in[4];   // [450]
    const float* b_hh   = (const float*)d_in[5];   // [450]
    const int*   ei     = (const int*)d_in[6];     // [2,NE]
    float* h = (float*)d_out;                      // [NN,150]

    char* p = (char*)d_ws;
    auto alloc = [&](size_t bytes) { char* r = p; p += (bytes + 255) & ~255ull; return r; };
    int*   off    = (int*)alloc((size_t)(NN + 1) * 4);
    int*   pos    = (int*)alloc((size_t)NN * 4);
    int*   deg    = (int*)alloc((size_t)NN * 4);
    int*   csr    = (int*)alloc((size_t)NE * 4);
    float* wiht   = (float*)alloc((size_t)G3 * HID * 4);
    float* whht   = (float*)alloc((size_t)G3 * HID * 4);
    float* fusedT = (float*)alloc((size_t)NL * HID * G3 * 4);
    float* aggr   = (float*)alloc((size_t)NN * HID * 4);

    hipMemsetAsync(deg, 0, (size_t)NN * 4, stream);
    int tb = (G3 * HID + 255) / 256;
    transpose_w<<<tb, 256, 0, stream>>>(w_ih, wiht);
    transpose_w<<<tb, 256, 0, stream>>>(w_hh, whht);
    build_fused<<<(NL * HID * G3 + 255) / 256, 256, 0, stream>>>(weight, wiht, fusedT);
    hist_deg<<<(NE + 255) / 256, 256, 0, stream>>>(ei, deg);
    scan_offsets<<<1, SCAN_T, 0, stream>>>(deg, off, pos);
    fill_csr<<<(NE + 255) / 256, 256, 0, stream>>>(ei, pos, csr);

    for (int l = 0; l < NL; ++l) {
        const float* hin = (l == 0) ? x : h;
        aggregate<<<(NN * 64 + 255) / 256, 256, 0, stream>>>(hin, off, csr, aggr);
        gru_cell<<<NN / MT, 192, 0, stream>>>(aggr, hin,
                                              fusedT + (size_t)l * HID * G3, whht,
                                              b_ih, b_hh, h);
    }
}

// Round 3
// 2906.405 us; speedup vs baseline: 2.9756x; 1.4601x over previous
//
#include <hip/hip_runtime.h>
#include <hip/hip_bf16.h>
#include <cmath>

#define HID 150
#define NN 100000
#define NE 1600000
#define NL 5
#define G3 (3*HID)          // 450
#define KP 320              // padded K: [aggr 0..149 | bias row 150 | pad | h 160..309 | pad]
#define NP 640              // padded N: 4 sections x 160 (r, z, i_n, h_n)
#define KS 10               // k-steps of 32
#define NT 40               // n-tiles of 16
#define BM 32
#define NNB ((NN + BM - 1) / BM)    // 3125 -> 3128? compute below
#define SCAN_T 1024
#define CHUNK 98

typedef __hip_bfloat16 bf16;
using short8 = __attribute__((ext_vector_type(8))) short;
using f32x4  = __attribute__((ext_vector_type(4))) float;

static __device__ __forceinline__ unsigned short bf_bits(float v) {
    __hip_bfloat16 h = __float2bfloat16(v);
    return *reinterpret_cast<unsigned short*>(&h);
}

// ---------------- build W fragments (per layer, MFMA B-frag order) ----------------
// Logical Wbig[l][k][j], j = sec*160 + f (sec: 0=r 1=z 2=i_n 3=h_n), k: 0..149 aggr,
// 150 bias(ones), 160..309 h, else 0.  fused[k][f'] = sum_t W_l[k][t] * w_ih[f'][t]
__global__ void build_wfrag(const float* __restrict__ W, const float* __restrict__ w_ih,
                            const float* __restrict__ w_hh, const float* __restrict__ b_ih,
                            const float* __restrict__ b_hh, bf16* __restrict__ wfrag) {
    int idx = blockIdx.x * 256 + threadIdx.x;
    if (idx >= NL * KP * NP) return;
    int j = idx % NP;
    int k = (idx / NP) % KP;
    int l = idx / (NP * KP);
    int sec = j / 160;
    int f = j - sec * 160;
    float v = 0.f;
    if (f < HID) {
        if (k < HID) {
            if (sec < 3) {  // aggr rows: fused = W_l @ w_ih^T (w_ih row sec*150+f)
                const float* Wl = W + (size_t)l * HID * HID + (size_t)k * HID;
                const float* wr = w_ih + (size_t)(sec * HID + f) * HID;
                float acc = 0.f;
                for (int t = 0; t < HID; ++t) acc += Wl[t] * wr[t];
                v = acc;
            }
        } else if (k == HID) {  // bias row (A has ones here)
            v = (sec == 0) ? b_ih[f] + b_hh[f]
              : (sec == 1) ? b_ih[HID + f] + b_hh[HID + f]
              : (sec == 2) ? b_ih[2 * HID + f]
                           : b_hh[2 * HID + f];
        } else if (k >= 160 && k < 160 + HID) {  // h rows
            int kk = k - 160;
            if (sec == 0)      v = w_hh[(size_t)f * HID + kk];
            else if (sec == 1) v = w_hh[(size_t)(HID + f) * HID + kk];
            else if (sec == 3) v = w_hh[(size_t)(2 * HID + f) * HID + kk];
        }
    }
    // scatter into fragment layout: lane holds B[k=quad*8+i][n=lane&15]
    int kstep = k >> 5, kq = (k >> 3) & 3, ki = k & 7;
    int ntile = j >> 4, nl = j & 15;
    int lane = kq * 16 + nl;
    wfrag[((((size_t)l * KS + kstep) * NT + ntile) * 64 + lane) * 8 + ki] = __float2bfloat16(v);
}

// ---------------- CSR build ----------------
__global__ void hist_deg(const int* __restrict__ ei, int* __restrict__ deg) {
    int e = blockIdx.x * blockDim.x + threadIdx.x;
    if (e < NE) atomicAdd(&deg[ei[NE + e]], 1);
}

__global__ void scan_offsets(const int* __restrict__ deg, int* __restrict__ off,
                             int* __restrict__ pos) {
    __shared__ int s[SCAN_T];
    int t = threadIdx.x;
    int lo = t * CHUNK;
    int hi = lo + CHUNK; if (hi > NN) hi = NN;
    int sum = 0;
    for (int i = lo; i < hi; ++i) sum += deg[i];
    s[t] = sum;
    __syncthreads();
    for (int d = 1; d < SCAN_T; d <<= 1) {
        int v = (t >= d) ? s[t - d] : 0;
        __syncthreads();
        s[t] += v;
        __syncthreads();
    }
    int base = s[t] - sum;
    for (int i = lo; i < hi; ++i) {
        off[i] = base; pos[i] = base;
        base += deg[i];
    }
    if (t == 0) off[NN] = s[SCAN_T - 1];
}

__global__ void fill_csr(const int* __restrict__ ei, int* __restrict__ pos,
                         int* __restrict__ csr) {
    int e = blockIdx.x * blockDim.x + threadIdx.x;
    if (e < NE) {
        int p = atomicAdd(&pos[ei[NE + e]], 1);
        csr[p] = ei[e];
    }
}

// ---------------- x -> Abuf h-region (bf16) ----------------
__global__ void init_h(const float* __restrict__ x, bf16* __restrict__ Abuf) {
    size_t i = (size_t)blockIdx.x * 256 + threadIdx.x;
    if (i >= (size_t)NN * HID) return;
    int m = (int)(i / HID), f = (int)(i - (size_t)m * HID);
    Abuf[(size_t)m * KP + 160 + f] = __float2bfloat16(x[i]);
}

// ---------------- aggregate: wave per node, gather bf16 h rows, write bf16 aggr ----------------
__global__ void aggregate(bf16* __restrict__ Abuf, const int* __restrict__ off,
                          const int* __restrict__ csr) {
    int node = (blockIdx.x * blockDim.x + threadIdx.x) >> 6;
    int lane = threadIdx.x & 63;
    if (node >= NN) return;
    int e0 = off[node], e1 = off[node + 1];
    float a0 = 0.f, a1 = 0.f, b0 = 0.f, b1 = 0.f;
    bool tail = lane < 11;   // uints 64..74 cover features 128..149
    for (int e = e0; e < e1; ++e) {
        const unsigned int* row = (const unsigned int*)(Abuf + (size_t)csr[e] * KP + 160);
        unsigned int p0 = row[lane];
        a0 += __uint_as_float((p0 & 0xffffu) << 16);
        a1 += __uint_as_float(p0 & 0xffff0000u);
        if (tail) {
            unsigned int p1 = row[64 + lane];
            b0 += __uint_as_float((p1 & 0xffffu) << 16);
            b1 += __uint_as_float(p1 & 0xffff0000u);
        }
    }
    unsigned int* out = (unsigned int*)(Abuf + (size_t)node * KP);
    out[lane] = (unsigned int)bf_bits(a0) | ((unsigned int)bf_bits(a1) << 16);
    if (tail) out[64 + lane] = (unsigned int)bf_bits(b0) | ((unsigned int)bf_bits(b1) << 16);
    // cols 150..159: ones column at 150, zeros elsewhere (uints 75..79)
    if (lane < 5) out[75 + lane] = (lane == 0) ? 0x00003F80u : 0u;
}

// ---------------- fused GEMM + GRU epilogue ----------------
// block: 256 thr = 4 waves (mw = wave>>1 m-tile, nw = wave&1 feature-half)
// wave computes 1 m-tile(16 rows) x 5 feature-groups x 4 sections = 20 mfma tiles
__global__ __launch_bounds__(256, 2)
void gemm_gru(const bf16* __restrict__ Abuf, const bf16* __restrict__ wfrag_l,
              const float* __restrict__ h_in, float* __restrict__ h_out,
              bf16* __restrict__ Abuf_w) {
    __shared__ __align__(16) bf16 As[BM * 328];   // row stride 328 (=164 words, +4 banks/row)
    int tid = threadIdx.x;
    int wave = tid >> 6, lane = tid & 63;
    int mw = wave >> 1, nw = wave & 1;
    int row0 = blockIdx.x * BM;

    for (int i = tid; i < BM * 40; i += 256) {
        int r = i / 40, seg = i - r * 40;
        *(float4*)(&As[r * 328 + seg * 8]) =
            *(const float4*)(Abuf + (size_t)(row0 + r) * KP + seg * 8);
    }
    __syncthreads();

    f32x4 acc[20];
#pragma unroll
    for (int t = 0; t < 20; ++t) acc[t] = (f32x4){0.f, 0.f, 0.f, 0.f};

    const bf16* a_base = &As[(mw * 16 + (lane & 15)) * 328 + (lane >> 4) * 8];
    for (int ks = 0; ks < KS; ++ks) {
        short8 a = *(const short8*)(a_base + ks * 32);
#pragma unroll
        for (int t = 0; t < 20; ++t) {
            int g = t >> 2, s = t & 3;
            int ntile = s * 10 + nw * 5 + g;
            short8 b = *(const short8*)(wfrag_l + ((size_t)(ks * NT + ntile) * 64 + lane) * 8);
            acc[t] = __builtin_amdgcn_mfma_f32_16x16x32_bf16(a, b, acc[t], 0, 0, 0);
        }
    }

    // epilogue: C layout col=lane&15, row=(lane>>4)*4+reg
    int col = lane & 15;
    int qrow = (lane >> 4) * 4;
#pragma unroll
    for (int g = 0; g < 5; ++g) {
        int f = (nw * 5 + g) * 16 + col;
        if (f < HID) {
            f32x4 ar = acc[g * 4 + 0], az = acc[g * 4 + 1];
            f32x4 an = acc[g * 4 + 2], ah = acc[g * 4 + 3];
#pragma unroll
            for (int v = 0; v < 4; ++v) {
                int m = row0 + mw * 16 + qrow + v;
                if (m < NN) {
                    float r = 1.f / (1.f + __expf(-ar[v]));
                    float z = 1.f / (1.f + __expf(-az[v]));
                    float n = tanhf(an[v] + r * ah[v]);
                    float hp = h_in[(size_t)m * HID + f];
                    float ho = (1.f - z) * n + z * hp;
                    h_out[(size_t)m * HID + f] = ho;
                    Abuf_w[(size_t)m * KP + 160 + f] = __float2bfloat16(ho);
                }
            }
        }
    }
}

extern "C" void kernel_launch(void* const* d_in, const int* in_sizes, int n_in,
                              void* d_out, int out_size, void* d_ws, size_t ws_size,
                              hipStream_t stream) {
    const float* x      = (const float*)d_in[0];
    const float* weight = (const float*)d_in[1];
    const float* w_ih   = (const float*)d_in[2];
    const float* w_hh   = (const float*)d_in[3];
    const float* b_ih   = (const float*)d_in[4];
    const float* b_hh   = (const float*)d_in[5];
    const int*   ei     = (const int*)d_in[6];
    float* h = (float*)d_out;

    const int nblk = (NN + BM - 1) / BM;          // 3125
    const size_t NNP = (size_t)nblk * BM;         // 100000 (multiple of 32) + guard below
    char* p = (char*)d_ws;
    auto alloc = [&](size_t bytes) { char* r = p; p += (bytes + 255) & ~255ull; return r; };
    int*  off   = (int*)alloc((size_t)(NN + 1) * 4);
    int*  pos   = (int*)alloc((size_t)NN * 4);
    int*  deg   = (int*)alloc((size_t)NN * 4);
    int*  csr   = (int*)alloc((size_t)NE * 4);
    bf16* wfrag = (bf16*)alloc((size_t)NL * KS * NT * 64 * 8 * 2);
    bf16* Abuf  = (bf16*)alloc((NNP + BM) * (size_t)KP * 2);

    hipMemsetAsync(deg, 0, (size_t)NN * 4, stream);
    build_wfrag<<<(NL * KP * NP + 255) / 256, 256, 0, stream>>>(weight, w_ih, w_hh, b_ih, b_hh, wfrag);
    hist_deg<<<(NE + 255) / 256, 256, 0, stream>>>(ei, deg);
    scan_offsets<<<1, SCAN_T, 0, stream>>>(deg, off, pos);
    fill_csr<<<(NE + 255) / 256, 256, 0, stream>>>(ei, pos, csr);
    init_h<<<(int)(((size_t)NN * HID + 255) / 256), 256, 0, stream>>>(x, Abuf);

    for (int l = 0; l < NL; ++l) {
        const float* hin = (l == 0) ? x : h;
        aggregate<<<(NN * 64 + 255) / 256, 256, 0, stream>>>(Abuf, off, csr);
        gemm_gru<<<nblk, 256, 0, stream>>>(Abuf, wfrag + (size_t)l * KS * NT * 512,
                                           hin, h, Abuf);
    }
}

// Round 4
// 2026.939 us; speedup vs baseline: 4.2667x; 1.4339x over previous
//
#include <hip/hip_runtime.h>
#include <hip/hip_bf16.h>
#include <cmath>

#define HID 150
#define NN 100000
#define NE 1600000
#define NL 5
#define G3 (3*HID)          // 450
#define KP 320              // padded K: [aggr 0..149 | bias row 150 | pad | h 160..309 | pad]
#define NP 640              // padded N: 4 sections x 160 (r, z, i_n, h_n)
#define KS 10               // k-steps of 32
#define NT 40               // n-tiles of 16
#define BM 64               // rows per block
#define SCAN_T 1024
#define CHUNK 98

typedef __hip_bfloat16 bf16;
using short8 = __attribute__((ext_vector_type(8))) short;
using f32x4  = __attribute__((ext_vector_type(4))) float;

static __device__ __forceinline__ unsigned short bf_bits(float v) {
    __hip_bfloat16 h = __float2bfloat16(v);
    return *reinterpret_cast<unsigned short*>(&h);
}

static __device__ __forceinline__ void gld_lds16(const void* g, void* l) {
    __builtin_amdgcn_global_load_lds(
        (const __attribute__((address_space(1))) void*)g,
        (__attribute__((address_space(3))) void*)l, 16, 0, 0);
}

// ---------------- build W fragments (per layer, MFMA B-frag order) ----------------
// Logical Wbig[l][k][j], j = sec*160 + f (sec: 0=r 1=z 2=i_n 3=h_n), k: 0..149 aggr,
// 150 bias(ones), 160..309 h, else 0.  fused[k][f'] = sum_t W_l[k][t] * w_ih[f'][t]
__global__ void build_wfrag(const float* __restrict__ W, const float* __restrict__ w_ih,
                            const float* __restrict__ w_hh, const float* __restrict__ b_ih,
                            const float* __restrict__ b_hh, bf16* __restrict__ wfrag) {
    int idx = blockIdx.x * 256 + threadIdx.x;
    if (idx >= NL * KP * NP) return;
    int j = idx % NP;
    int k = (idx / NP) % KP;
    int l = idx / (NP * KP);
    int sec = j / 160;
    int f = j - sec * 160;
    float v = 0.f;
    if (f < HID) {
        if (k < HID) {
            if (sec < 3) {  // aggr rows: fused = W_l @ w_ih^T (w_ih row sec*150+f)
                const float* Wl = W + (size_t)l * HID * HID + (size_t)k * HID;
                const float* wr = w_ih + (size_t)(sec * HID + f) * HID;
                float acc = 0.f;
                for (int t = 0; t < HID; ++t) acc += Wl[t] * wr[t];
                v = acc;
            }
        } else if (k == HID) {  // bias row (A has ones here)
            v = (sec == 0) ? b_ih[f] + b_hh[f]
              : (sec == 1) ? b_ih[HID + f] + b_hh[HID + f]
              : (sec == 2) ? b_ih[2 * HID + f]
                           : b_hh[2 * HID + f];
        } else if (k >= 160 && k < 160 + HID) {  // h rows
            int kk = k - 160;
            if (sec == 0)      v = w_hh[(size_t)f * HID + kk];
            else if (sec == 1) v = w_hh[(size_t)(HID + f) * HID + kk];
            else if (sec == 3) v = w_hh[(size_t)(2 * HID + f) * HID + kk];
        }
    }
    // fragment layout: lane holds B[k=quad*8+i][n=lane&15]
    int kstep = k >> 5, kq = (k >> 3) & 3, ki = k & 7;
    int ntile = j >> 4, nl = j & 15;
    int lane = kq * 16 + nl;
    wfrag[((((size_t)l * KS + kstep) * NT + ntile) * 64 + lane) * 8 + ki] = __float2bfloat16(v);
}

// ---------------- CSR build ----------------
__global__ void hist_deg(const int* __restrict__ ei, int* __restrict__ deg) {
    int e = blockIdx.x * blockDim.x + threadIdx.x;
    if (e < NE) atomicAdd(&deg[ei[NE + e]], 1);
}

__global__ void scan_offsets(const int* __restrict__ deg, int* __restrict__ off,
                             int* __restrict__ pos) {
    __shared__ int s[SCAN_T];
    int t = threadIdx.x;
    int lo = t * CHUNK;
    int hi = lo + CHUNK; if (hi > NN) hi = NN;
    int sum = 0;
    for (int i = lo; i < hi; ++i) sum += deg[i];
    s[t] = sum;
    __syncthreads();
    for (int d = 1; d < SCAN_T; d <<= 1) {
        int v = (t >= d) ? s[t - d] : 0;
        __syncthreads();
        s[t] += v;
        __syncthreads();
    }
    int base = s[t] - sum;
    for (int i = lo; i < hi; ++i) {
        off[i] = base; pos[i] = base;
        base += deg[i];
    }
    if (t == 0) off[NN] = s[SCAN_T - 1];
}

__global__ void fill_csr(const int* __restrict__ ei, int* __restrict__ pos,
                         int* __restrict__ csr) {
    int e = blockIdx.x * blockDim.x + threadIdx.x;
    if (e < NE) {
        int p = atomicAdd(&pos[ei[NE + e]], 1);
        csr[p] = ei[e];
    }
}

// ---------------- x -> Abuf h-region (bf16) ----------------
__global__ void init_h(const float* __restrict__ x, bf16* __restrict__ Abuf) {
    size_t i = (size_t)blockIdx.x * 256 + threadIdx.x;
    if (i >= (size_t)NN * HID) return;
    int m = (int)(i / HID), f = (int)(i - (size_t)m * HID);
    Abuf[(size_t)m * KP + 160 + f] = __float2bfloat16(x[i]);
}

// ---------------- aggregate: wave per node, gather bf16 h rows, write bf16 aggr ----------------
__global__ void aggregate(bf16* __restrict__ Abuf, const int* __restrict__ off,
                          const int* __restrict__ csr) {
    int node = (blockIdx.x * blockDim.x + threadIdx.x) >> 6;
    int lane = threadIdx.x & 63;
    if (node >= NN) return;
    int e0 = off[node], e1 = off[node + 1];
    float a0 = 0.f, a1 = 0.f, b0 = 0.f, b1 = 0.f;
    bool tail = lane < 11;   // uints 64..74 cover features 128..149
    for (int e = e0; e < e1; ++e) {
        const unsigned int* row = (const unsigned int*)(Abuf + (size_t)csr[e] * KP + 160);
        unsigned int p0 = row[lane];
        a0 += __uint_as_float((p0 & 0xffffu) << 16);
        a1 += __uint_as_float(p0 & 0xffff0000u);
        if (tail) {
            unsigned int p1 = row[64 + lane];
            b0 += __uint_as_float((p1 & 0xffffu) << 16);
            b1 += __uint_as_float(p1 & 0xffff0000u);
        }
    }
    unsigned int* out = (unsigned int*)(Abuf + (size_t)node * KP);
    out[lane] = (unsigned int)bf_bits(a0) | ((unsigned int)bf_bits(a1) << 16);
    if (tail) out[64 + lane] = (unsigned int)bf_bits(b0) | ((unsigned int)bf_bits(b1) << 16);
    // cols 150..159: ones column at 150, zeros elsewhere (uints 75..79)
    if (lane < 5) out[75 + lane] = (lane == 0) ? 0x00003F80u : 0u;
}

// ---------------- fused GEMM + GRU epilogue ----------------
// 256 thr = 4 waves: mh = wave>>1 (32-row half), nh = wave&1 (5-fgroup half)
// A (all 10 ks) + B (per-ks, 40 tiles) staged in LDS via global_load_lds.
// Each wave: 2 m-tiles x 20 ntiles, B frag reused 2x in reg, 8x per block via LDS.
__global__ __launch_bounds__(256, 2)
void gemm_gru(const bf16* __restrict__ Abuf, const bf16* __restrict__ wfrag_l,
              const float* __restrict__ h_in, float* __restrict__ h_out,
              bf16* __restrict__ Abuf_w) {
    __shared__ __align__(16) bf16 As[KS * BM * 32];   // [ks][row][32k]  40 KB
    __shared__ __align__(16) bf16 Bs[NT * 64 * 8];    // [ntile][lane][8] 40 KB
    int tid = threadIdx.x;
    int wave = tid >> 6, lane = tid & 63;
    int mh = wave >> 1, nh = wave & 1;
    int row0 = blockIdx.x * BM;

    // ---- stage all of A: chunk c: ks=c/256? no: per-ks block = 64 rows * 64 B = 256 chunks
    {
        const char* gbase = (const char*)(Abuf + (size_t)row0 * KP);
        char* lbase = (char*)As;
#pragma unroll
        for (int it = 0; it < 10; ++it) {
            int c = it * 256 + tid;          // 0..2559
            int ks = c >> 8;                 // c / 256
            int rem = c & 255;
            int r = rem >> 2, q = rem & 3;
            gld_lds16(gbase + (size_t)r * (KP * 2) + ks * 64 + q * 16,
                      lbase + (size_t)c * 16);
        }
    }
    // ---- stage B(ks=0)
    {
        const char* gb = (const char*)wfrag_l;
        char* lb = (char*)Bs;
#pragma unroll
        for (int it = 0; it < 10; ++it) {
            int c = it * 256 + tid;
            gld_lds16(gb + (size_t)c * 16, lb + (size_t)c * 16);
        }
    }
    __syncthreads();

    f32x4 acc[2][20];
#pragma unroll
    for (int mt = 0; mt < 2; ++mt)
#pragma unroll
        for (int t = 0; t < 20; ++t) acc[mt][t] = (f32x4){0.f, 0.f, 0.f, 0.f};

    int col = lane & 15, q = lane >> 4;
    for (int ks = 0; ks < KS; ++ks) {
        // a-frags for this ks
        short8 a0 = *(const short8*)(As + ((size_t)(ks * BM + mh * 32 + col) * 32 + q * 8));
        short8 a1 = *(const short8*)(As + ((size_t)(ks * BM + mh * 32 + 16 + col) * 32 + q * 8));
#pragma unroll
        for (int g = 0; g < 5; ++g) {
#pragma unroll
            for (int s = 0; s < 4; ++s) {
                int nt = s * 10 + nh * 5 + g;
                short8 b = *(const short8*)(Bs + ((size_t)(nt * 64 + lane) * 8));
                acc[0][g * 4 + s] = __builtin_amdgcn_mfma_f32_16x16x32_bf16(a0, b, acc[0][g * 4 + s], 0, 0, 0);
                acc[1][g * 4 + s] = __builtin_amdgcn_mfma_f32_16x16x32_bf16(a1, b, acc[1][g * 4 + s], 0, 0, 0);
            }
        }
        __syncthreads();   // done reading Bs
        if (ks < KS - 1) {
            const char* gb = (const char*)(wfrag_l + (size_t)(ks + 1) * NT * 64 * 8);
            char* lb = (char*)Bs;
#pragma unroll
            for (int it = 0; it < 10; ++it) {
                int c = it * 256 + tid;
                gld_lds16(gb + (size_t)c * 16, lb + (size_t)c * 16);
            }
            __syncthreads();
        }
    }

    // epilogue: C layout col=lane&15, row=(lane>>4)*4+reg
    int qrow = q * 4;
#pragma unroll
    for (int mt = 0; mt < 2; ++mt) {
#pragma unroll
        for (int g = 0; g < 5; ++g) {
            int f = (nh * 5 + g) * 16 + col;
            if (f < HID) {
                f32x4 ar = acc[mt][g * 4 + 0], az = acc[mt][g * 4 + 1];
                f32x4 an = acc[mt][g * 4 + 2], ah = acc[mt][g * 4 + 3];
#pragma unroll
                for (int v = 0; v < 4; ++v) {
                    int m = row0 + mh * 32 + mt * 16 + qrow + v;
                    if (m < NN) {
                        float r = 1.f / (1.f + __expf(-ar[v]));
                        float z = 1.f / (1.f + __expf(-az[v]));
                        float n = tanhf(an[v] + r * ah[v]);
                        float hp = h_in[(size_t)m * HID + f];
                        float ho = (1.f - z) * n + z * hp;
                        h_out[(size_t)m * HID + f] = ho;
                        Abuf_w[(size_t)m * KP + 160 + f] = __float2bfloat16(ho);
                    }
                }
            }
        }
    }
}

extern "C" void kernel_launch(void* const* d_in, const int* in_sizes, int n_in,
                              void* d_out, int out_size, void* d_ws, size_t ws_size,
                              hipStream_t stream) {
    const float* x      = (const float*)d_in[0];
    const float* weight = (const float*)d_in[1];
    const float* w_ih   = (const float*)d_in[2];
    const float* w_hh   = (const float*)d_in[3];
    const float* b_ih   = (const float*)d_in[4];
    const float* b_hh   = (const float*)d_in[5];
    const int*   ei     = (const int*)d_in[6];
    float* h = (float*)d_out;

    const int nblk = (NN + BM - 1) / BM;          // 1563
    const size_t NNP = (size_t)nblk * BM;         // 100032 (guard rows)
    char* p = (char*)d_ws;
    auto alloc = [&](size_t bytes) { char* r = p; p += (bytes + 255) & ~255ull; return r; };
    int*  off   = (int*)alloc((size_t)(NN + 1) * 4);
    int*  pos   = (int*)alloc((size_t)NN * 4);
    int*  deg   = (int*)alloc((size_t)NN * 4);
    int*  csr   = (int*)alloc((size_t)NE * 4);
    bf16* wfrag = (bf16*)alloc((size_t)NL * KS * NT * 64 * 8 * 2);
    bf16* Abuf  = (bf16*)alloc((NNP + BM) * (size_t)KP * 2);

    hipMemsetAsync(deg, 0, (size_t)NN * 4, stream);
    build_wfrag<<<(NL * KP * NP + 255) / 256, 256, 0, stream>>>(weight, w_ih, w_hh, b_ih, b_hh, wfrag);
    hist_deg<<<(NE + 255) / 256, 256, 0, stream>>>(ei, deg);
    scan_offsets<<<1, SCAN_T, 0, stream>>>(deg, off, pos);
    fill_csr<<<(NE + 255) / 256, 256, 0, stream>>>(ei, pos, csr);
    init_h<<<(int)(((size_t)NN * HID + 255) / 256), 256, 0, stream>>>(x, Abuf);

    for (int l = 0; l < NL; ++l) {
        const float* hin = (l == 0) ? x : h;
        aggregate<<<(NN * 64 + 255) / 256, 256, 0, stream>>>(Abuf, off, csr);
        gemm_gru<<<nblk, 256, 0, stream>>>(Abuf, wfrag + (size_t)l * KS * NT * 512,
                                           hin, h, Abuf);
    }
}

// Round 5
// 1806.730 us; speedup vs baseline: 4.7867x; 1.1219x over previous
//
#include <hip/hip_runtime.h>
#include <hip/hip_bf16.h>
#include <cmath>

#define HID 150
#define NN 100000
#define NE 1600000
#define NL 5
#define G3 (3*HID)          // 450
#define KP 320              // padded K: [aggr 0..149 | bias row 150 | pad | h 160..309 | pad]
#define NP 640              // padded N: 4 sections x 160 (r, z, i_n, h_n)
#define KS 10               // k-steps of 32
#define NT 40               // n-tiles of 16
#define BM 64               // rows per block
#define NPART 98            // ceil(25000 int4 / 256)

typedef __hip_bfloat16 bf16;
using short8 = __attribute__((ext_vector_type(8))) short;
using f32x4  = __attribute__((ext_vector_type(4))) float;

static __device__ __forceinline__ unsigned short bf_bits(float v) {
    __hip_bfloat16 h = __float2bfloat16(v);
    return *reinterpret_cast<unsigned short*>(&h);
}

static __device__ __forceinline__ void gld_lds16(const void* g, void* l) {
    __builtin_amdgcn_global_load_lds(
        (const __attribute__((address_space(1))) void*)g,
        (__attribute__((address_space(3))) void*)l, 16, 0, 0);
}

// ---------------- build W fragments (per layer, MFMA B-frag order) ----------------
__global__ void build_wfrag(const float* __restrict__ W, const float* __restrict__ w_ih,
                            const float* __restrict__ w_hh, const float* __restrict__ b_ih,
                            const float* __restrict__ b_hh, bf16* __restrict__ wfrag) {
    int idx = blockIdx.x * 256 + threadIdx.x;
    if (idx >= NL * KP * NP) return;
    int j = idx % NP;
    int k = (idx / NP) % KP;
    int l = idx / (NP * KP);
    int sec = j / 160;
    int f = j - sec * 160;
    float v = 0.f;
    if (f < HID) {
        if (k < HID) {
            if (sec < 3) {  // aggr rows: fused = W_l @ w_ih^T
                const float* Wl = W + (size_t)l * HID * HID + (size_t)k * HID;
                const float* wr = w_ih + (size_t)(sec * HID + f) * HID;
                float acc = 0.f;
                for (int t = 0; t < HID; ++t) acc += Wl[t] * wr[t];
                v = acc;
            }
        } else if (k == HID) {  // bias row (A has ones here)
            v = (sec == 0) ? b_ih[f] + b_hh[f]
              : (sec == 1) ? b_ih[HID + f] + b_hh[HID + f]
              : (sec == 2) ? b_ih[2 * HID + f]
                           : b_hh[2 * HID + f];
        } else if (k >= 160 && k < 160 + HID) {  // h rows
            int kk = k - 160;
            if (sec == 0)      v = w_hh[(size_t)f * HID + kk];
            else if (sec == 1) v = w_hh[(size_t)(HID + f) * HID + kk];
            else if (sec == 3) v = w_hh[(size_t)(2 * HID + f) * HID + kk];
        }
    }
    int kstep = k >> 5, kq = (k >> 3) & 3, ki = k & 7;
    int ntile = j >> 4, nl = j & 15;
    int lane = kq * 16 + nl;
    wfrag[((((size_t)l * KS + kstep) * NT + ntile) * 64 + lane) * 8 + ki] = __float2bfloat16(v);
}

// ---------------- CSR build ----------------
__global__ void hist_deg(const int* __restrict__ ei, int* __restrict__ deg) {
    int e = blockIdx.x * blockDim.x + threadIdx.x;
    if (e < NE) atomicAdd(&deg[ei[NE + e]], 1);
}

// phase 1: per-block (1024 ints) partial sums
__global__ void scan_part(const int* __restrict__ deg, int* __restrict__ part) {
    int gid = blockIdx.x * 256 + threadIdx.x;     // int4 index
    int4 v = {0, 0, 0, 0};
    if (gid * 4 < NN) v = ((const int4*)deg)[gid];
    int s = v.x + v.y + v.z + v.w;
    __shared__ int red[4];
    for (int d = 32; d; d >>= 1) s += __shfl_down(s, d, 64);
    if ((threadIdx.x & 63) == 0) red[threadIdx.x >> 6] = s;
    __syncthreads();
    if (threadIdx.x == 0) part[blockIdx.x] = red[0] + red[1] + red[2] + red[3];
}

// phase 2: exclusive-scan the 98 partials in one tiny block; write off[NN]
__global__ void scan_part2(int* __restrict__ part, int* __restrict__ off) {
    __shared__ int s[128];
    int t = threadIdx.x;
    int v = (t < NPART) ? part[t] : 0;
    s[t] = v;
    __syncthreads();
    for (int d = 1; d < 128; d <<= 1) {
        int u = (t >= d) ? s[t - d] : 0;
        __syncthreads();
        s[t] += u;
        __syncthreads();
    }
    if (t < NPART) part[t] = s[t] - v;
    if (t == 127) off[NN] = s[127];
}

// phase 3: in-block scan + write off/pos (int4)
__global__ void scan_write(const int* __restrict__ deg, const int* __restrict__ part,
                           int* __restrict__ off, int* __restrict__ pos) {
    __shared__ int s[256];
    int t = threadIdx.x;
    int gid = blockIdx.x * 256 + t;
    int4 v = {0, 0, 0, 0};
    if (gid * 4 < NN) v = ((const int4*)deg)[gid];
    int sum = v.x + v.y + v.z + v.w;
    s[t] = sum;
    __syncthreads();
    for (int d = 1; d < 256; d <<= 1) {
        int u = (t >= d) ? s[t - d] : 0;
        __syncthreads();
        s[t] += u;
        __syncthreads();
    }
    int base = part[blockIdx.x] + s[t] - sum;
    if (gid * 4 < NN) {
        int4 o;
        o.x = base;
        o.y = base + v.x;
        o.z = o.y + v.y;
        o.w = o.z + v.z;
        ((int4*)off)[gid] = o;
        ((int4*)pos)[gid] = o;
    }
}

__global__ void fill_csr(const int* __restrict__ ei, int* __restrict__ pos,
                         int* __restrict__ csr) {
    int e = blockIdx.x * blockDim.x + threadIdx.x;
    if (e < NE) {
        int p = atomicAdd(&pos[ei[NE + e]], 1);
        csr[p] = ei[e];
    }
}

// ---------------- x -> Abuf h-region (bf16) ----------------
__global__ void init_h(const float* __restrict__ x, bf16* __restrict__ Abuf) {
    size_t i = (size_t)blockIdx.x * 256 + threadIdx.x;
    if (i >= (size_t)NN * HID) return;
    int m = (int)(i / HID), f = (int)(i - (size_t)m * HID);
    Abuf[(size_t)m * KP + 160 + f] = __float2bfloat16(x[i]);
}

// ---------------- aggregate: wave per node, gather bf16 h rows, write bf16 aggr ----------------
__global__ void aggregate(bf16* __restrict__ Abuf, const int* __restrict__ off,
                          const int* __restrict__ csr) {
    int node = (blockIdx.x * blockDim.x + threadIdx.x) >> 6;
    int lane = threadIdx.x & 63;
    if (node >= NN) return;
    int e0 = off[node], e1 = off[node + 1];
    float a0 = 0.f, a1 = 0.f, b0 = 0.f, b1 = 0.f;
    bool tail = lane < 11;   // uints 64..74 cover features 128..149
    for (int e = e0; e < e1; ++e) {
        const unsigned int* row = (const unsigned int*)(Abuf + (size_t)csr[e] * KP + 160);
        unsigned int p0 = row[lane];
        a0 += __uint_as_float((p0 & 0xffffu) << 16);
        a1 += __uint_as_float(p0 & 0xffff0000u);
        if (tail) {
            unsigned int p1 = row[64 + lane];
            b0 += __uint_as_float((p1 & 0xffffu) << 16);
            b1 += __uint_as_float(p1 & 0xffff0000u);
        }
    }
    unsigned int* out = (unsigned int*)(Abuf + (size_t)node * KP);
    out[lane] = (unsigned int)bf_bits(a0) | ((unsigned int)bf_bits(a1) << 16);
    if (tail) out[64 + lane] = (unsigned int)bf_bits(b0) | ((unsigned int)bf_bits(b1) << 16);
    if (lane < 5) out[75 + lane] = (lane == 0) ? 0x00003F80u : 0u;
}

// ---------------- fused GEMM + GRU epilogue ----------------
__global__ __launch_bounds__(256, 2)
void gemm_gru(const bf16* __restrict__ Abuf, const bf16* __restrict__ wfrag_l,
              const float* __restrict__ h_in, float* __restrict__ h_out,
              bf16* __restrict__ Abuf_w) {
    __shared__ __align__(16) bf16 As[KS * BM * 32];   // [ks][row][32k]  40 KB
    __shared__ __align__(16) bf16 Bs[NT * 64 * 8];    // [ntile][lane][8] 40 KB
    int tid = threadIdx.x;
    int wave = tid >> 6, lane = tid & 63;
    int mh = wave >> 1, nh = wave & 1;
    int row0 = blockIdx.x * BM;

    {
        const char* gbase = (const char*)(Abuf + (size_t)row0 * KP);
        char* lbase = (char*)As;
#pragma unroll
        for (int it = 0; it < 10; ++it) {
            int c = it * 256 + tid;
            int ks = c >> 8;
            int rem = c & 255;
            int r = rem >> 2, q = rem & 3;
            gld_lds16(gbase + (size_t)r * (KP * 2) + ks * 64 + q * 16,
                      lbase + (size_t)c * 16);
        }
    }
    {
        const char* gb = (const char*)wfrag_l;
        char* lb = (char*)Bs;
#pragma unroll
        for (int it = 0; it < 10; ++it) {
            int c = it * 256 + tid;
            gld_lds16(gb + (size_t)c * 16, lb + (size_t)c * 16);
        }
    }
    __syncthreads();

    f32x4 acc[2][20];
#pragma unroll
    for (int mt = 0; mt < 2; ++mt)
#pragma unroll
        for (int t = 0; t < 20; ++t) acc[mt][t] = (f32x4){0.f, 0.f, 0.f, 0.f};

    int col = lane & 15, q = lane >> 4;
    for (int ks = 0; ks < KS; ++ks) {
        short8 a0 = *(const short8*)(As + ((size_t)(ks * BM + mh * 32 + col) * 32 + q * 8));
        short8 a1 = *(const short8*)(As + ((size_t)(ks * BM + mh * 32 + 16 + col) * 32 + q * 8));
#pragma unroll
        for (int g = 0; g < 5; ++g) {
#pragma unroll
            for (int s = 0; s < 4; ++s) {
                int nt = s * 10 + nh * 5 + g;
                short8 b = *(const short8*)(Bs + ((size_t)(nt * 64 + lane) * 8));
                acc[0][g * 4 + s] = __builtin_amdgcn_mfma_f32_16x16x32_bf16(a0, b, acc[0][g * 4 + s], 0, 0, 0);
                acc[1][g * 4 + s] = __builtin_amdgcn_mfma_f32_16x16x32_bf16(a1, b, acc[1][g * 4 + s], 0, 0, 0);
            }
        }
        __syncthreads();
        if (ks < KS - 1) {
            const char* gb = (const char*)(wfrag_l + (size_t)(ks + 1) * NT * 64 * 8);
            char* lb = (char*)Bs;
#pragma unroll
            for (int it = 0; it < 10; ++it) {
                int c = it * 256 + tid;
                gld_lds16(gb + (size_t)c * 16, lb + (size_t)c * 16);
            }
            __syncthreads();
        }
    }

    int qrow = q * 4;
#pragma unroll
    for (int mt = 0; mt < 2; ++mt) {
#pragma unroll
        for (int g = 0; g < 5; ++g) {
            int f = (nh * 5 + g) * 16 + col;
            if (f < HID) {
                f32x4 ar = acc[mt][g * 4 + 0], az = acc[mt][g * 4 + 1];
                f32x4 an = acc[mt][g * 4 + 2], ah = acc[mt][g * 4 + 3];
#pragma unroll
                for (int v = 0; v < 4; ++v) {
                    int m = row0 + mh * 32 + mt * 16 + qrow + v;
                    if (m < NN) {
                        float r = 1.f / (1.f + __expf(-ar[v]));
                        float z = 1.f / (1.f + __expf(-az[v]));
                        float n = tanhf(an[v] + r * ah[v]);
                        float hp = h_in[(size_t)m * HID + f];
                        float ho = (1.f - z) * n + z * hp;
                        h_out[(size_t)m * HID + f] = ho;
                        Abuf_w[(size_t)m * KP + 160 + f] = __float2bfloat16(ho);
                    }
                }
            }
        }
    }
}

extern "C" void kernel_launch(void* const* d_in, const int* in_sizes, int n_in,
                              void* d_out, int out_size, void* d_ws, size_t ws_size,
                              hipStream_t stream) {
    const float* x      = (const float*)d_in[0];
    const float* weight = (const float*)d_in[1];
    const float* w_ih   = (const float*)d_in[2];
    const float* w_hh   = (const float*)d_in[3];
    const float* b_ih   = (const float*)d_in[4];
    const float* b_hh   = (const float*)d_in[5];
    const int*   ei     = (const int*)d_in[6];
    float* h = (float*)d_out;

    const int nblk = (NN + BM - 1) / BM;          // 1563
    const size_t NNP = (size_t)nblk * BM;
    char* p = (char*)d_ws;
    auto alloc = [&](size_t bytes) { char* r = p; p += (bytes + 255) & ~255ull; return r; };
    int*  off   = (int*)alloc((size_t)(NN + 1) * 4);
    int*  pos   = (int*)alloc((size_t)NN * 4);
    int*  deg   = (int*)alloc((size_t)NN * 4);
    int*  part  = (int*)alloc((size_t)NPART * 4);
    int*  csr   = (int*)alloc((size_t)NE * 4);
    bf16* wfrag = (bf16*)alloc((size_t)NL * KS * NT * 64 * 8 * 2);
    bf16* Abuf  = (bf16*)alloc((NNP + BM) * (size_t)KP * 2);

    hipMemsetAsync(deg, 0, (size_t)NN * 4, stream);
    build_wfrag<<<(NL * KP * NP + 255) / 256, 256, 0, stream>>>(weight, w_ih, w_hh, b_ih, b_hh, wfrag);
    hist_deg<<<(NE + 255) / 256, 256, 0, stream>>>(ei, deg);
    scan_part<<<NPART, 256, 0, stream>>>(deg, part);
    scan_part2<<<1, 128, 0, stream>>>(part, off);
    scan_write<<<NPART, 256, 0, stream>>>(deg, part, off, pos);
    fill_csr<<<(NE + 255) / 256, 256, 0, stream>>>(ei, pos, csr);
    init_h<<<(int)(((size_t)NN * HID + 255) / 256), 256, 0, stream>>>(x, Abuf);

    for (int l = 0; l < NL; ++l) {
        const float* hin = (l == 0) ? x : h;
        aggregate<<<(NN * 64 + 255) / 256, 256, 0, stream>>>(Abuf, off, csr);
        gemm_gru<<<nblk, 256, 0, stream>>>(Abuf, wfrag + (size_t)l * KS * NT * 512,
                                           hin, h, Abuf);
    }
}

// Round 6
// 1405.649 us; speedup vs baseline: 6.1526x; 1.2853x over previous
//
#include <hip/hip_runtime.h>
#include <hip/hip_bf16.h>
#include <cmath>

#define HID 150
#define NN 100000
#define NE 1600000
#define NL 5
#define G3 (3*HID)          // 450
#define KP 320              // padded K: [aggr 0..149 | bias row 150 | pad | h 160..309 | pad]
#define NP 640              // padded N: 4 sections x 160 (r, z, i_n, h_n)
#define KS 10               // k-steps of 32
#define NT 40               // n-tiles of 16
#define BM 64               // rows per block
#define NPART 98            // ceil(25000 int4 / 256)

typedef __hip_bfloat16 bf16;
using short8 = __attribute__((ext_vector_type(8))) short;
using f32x4  = __attribute__((ext_vector_type(4))) float;

static __device__ __forceinline__ unsigned short bf_bits(float v) {
    __hip_bfloat16 h = __float2bfloat16(v);
    return *reinterpret_cast<unsigned short*>(&h);
}

static __device__ __forceinline__ float blo(unsigned int p) {
    return __uint_as_float((p & 0xffffu) << 16);
}
static __device__ __forceinline__ float bhi(unsigned int p) {
    return __uint_as_float(p & 0xffff0000u);
}

static __device__ __forceinline__ void gld_lds16(const void* g, void* l) {
    __builtin_amdgcn_global_load_lds(
        (const __attribute__((address_space(1))) void*)g,
        (__attribute__((address_space(3))) void*)l, 16, 0, 0);
}

// ---------------- build W fragments (per layer, MFMA B-frag order) ----------------
__global__ void build_wfrag(const float* __restrict__ W, const float* __restrict__ w_ih,
                            const float* __restrict__ w_hh, const float* __restrict__ b_ih,
                            const float* __restrict__ b_hh, bf16* __restrict__ wfrag) {
    int idx = blockIdx.x * 256 + threadIdx.x;
    if (idx >= NL * KP * NP) return;
    int j = idx % NP;
    int k = (idx / NP) % KP;
    int l = idx / (NP * KP);
    int sec = j / 160;
    int f = j - sec * 160;
    float v = 0.f;
    if (f < HID) {
        if (k < HID) {
            if (sec < 3) {  // aggr rows: fused = W_l @ w_ih^T
                const float* Wl = W + (size_t)l * HID * HID + (size_t)k * HID;
                const float* wr = w_ih + (size_t)(sec * HID + f) * HID;
                float acc = 0.f;
                for (int t = 0; t < HID; ++t) acc += Wl[t] * wr[t];
                v = acc;
            }
        } else if (k == HID) {  // bias row (A has ones here)
            v = (sec == 0) ? b_ih[f] + b_hh[f]
              : (sec == 1) ? b_ih[HID + f] + b_hh[HID + f]
              : (sec == 2) ? b_ih[2 * HID + f]
                           : b_hh[2 * HID + f];
        } else if (k >= 160 && k < 160 + HID) {  // h rows
            int kk = k - 160;
            if (sec == 0)      v = w_hh[(size_t)f * HID + kk];
            else if (sec == 1) v = w_hh[(size_t)(HID + f) * HID + kk];
            else if (sec == 3) v = w_hh[(size_t)(2 * HID + f) * HID + kk];
        }
    }
    int kstep = k >> 5, kq = (k >> 3) & 3, ki = k & 7;
    int ntile = j >> 4, nl = j & 15;
    int lane = kq * 16 + nl;
    wfrag[((((size_t)l * KS + kstep) * NT + ntile) * 64 + lane) * 8 + ki] = __float2bfloat16(v);
}

// ---------------- CSR build ----------------
__global__ void hist_deg(const int* __restrict__ ei, int* __restrict__ deg) {
    int e = blockIdx.x * blockDim.x + threadIdx.x;
    if (e < NE) atomicAdd(&deg[ei[NE + e]], 1);
}

__global__ void scan_part(const int* __restrict__ deg, int* __restrict__ part) {
    int gid = blockIdx.x * 256 + threadIdx.x;     // int4 index
    int4 v = {0, 0, 0, 0};
    if (gid * 4 < NN) v = ((const int4*)deg)[gid];
    int s = v.x + v.y + v.z + v.w;
    __shared__ int red[4];
    for (int d = 32; d; d >>= 1) s += __shfl_down(s, d, 64);
    if ((threadIdx.x & 63) == 0) red[threadIdx.x >> 6] = s;
    __syncthreads();
    if (threadIdx.x == 0) part[blockIdx.x] = red[0] + red[1] + red[2] + red[3];
}

__global__ void scan_part2(int* __restrict__ part, int* __restrict__ off) {
    __shared__ int s[128];
    int t = threadIdx.x;
    int v = (t < NPART) ? part[t] : 0;
    s[t] = v;
    __syncthreads();
    for (int d = 1; d < 128; d <<= 1) {
        int u = (t >= d) ? s[t - d] : 0;
        __syncthreads();
        s[t] += u;
        __syncthreads();
    }
    if (t < NPART) part[t] = s[t] - v;
    if (t == 127) off[NN] = s[127];
}

__global__ void scan_write(const int* __restrict__ deg, const int* __restrict__ part,
                           int* __restrict__ off, int* __restrict__ pos) {
    __shared__ int s[256];
    int t = threadIdx.x;
    int gid = blockIdx.x * 256 + t;
    int4 v = {0, 0, 0, 0};
    if (gid * 4 < NN) v = ((const int4*)deg)[gid];
    int sum = v.x + v.y + v.z + v.w;
    s[t] = sum;
    __syncthreads();
    for (int d = 1; d < 256; d <<= 1) {
        int u = (t >= d) ? s[t - d] : 0;
        __syncthreads();
        s[t] += u;
        __syncthreads();
    }
    int base = part[blockIdx.x] + s[t] - sum;
    if (gid * 4 < NN) {
        int4 o;
        o.x = base;
        o.y = base + v.x;
        o.z = o.y + v.y;
        o.w = o.z + v.z;
        ((int4*)off)[gid] = o;
        ((int4*)pos)[gid] = o;
    }
}

__global__ void fill_csr(const int* __restrict__ ei, int* __restrict__ pos,
                         int* __restrict__ csr) {
    int e = blockIdx.x * blockDim.x + threadIdx.x;
    if (e < NE) {
        int p = atomicAdd(&pos[ei[NE + e]], 1);
        csr[p] = ei[e];
    }
}

// ---------------- x -> Abuf h-region (bf16) ----------------
__global__ void init_h(const float* __restrict__ x, bf16* __restrict__ Abuf) {
    size_t i = (size_t)blockIdx.x * 256 + threadIdx.x;
    if (i >= (size_t)NN * HID) return;
    int m = (int)(i / HID), f = (int)(i - (size_t)m * HID);
    Abuf[(size_t)m * KP + 160 + f] = __float2bfloat16(x[i]);
}

// ---------------- aggregate: wave per node, 4-deep pipelined gather ----------------
__global__ void aggregate(bf16* __restrict__ Abuf, const int* __restrict__ off,
                          const int* __restrict__ csr) {
    int node = (blockIdx.x * blockDim.x + threadIdx.x) >> 6;
    int lane = threadIdx.x & 63;
    if (node >= NN) return;
    int e0 = off[node], e1 = off[node + 1];
    float a0 = 0.f, a1 = 0.f, b0 = 0.f, b1 = 0.f;
    bool tail = lane < 11;   // uints 64..74 cover features 128..149
    int e = e0;
    for (; e + 4 <= e1; e += 4) {
        const unsigned int* r0 = (const unsigned int*)(Abuf + (size_t)csr[e]     * KP + 160);
        const unsigned int* r1 = (const unsigned int*)(Abuf + (size_t)csr[e + 1] * KP + 160);
        const unsigned int* r2 = (const unsigned int*)(Abuf + (size_t)csr[e + 2] * KP + 160);
        const unsigned int* r3 = (const unsigned int*)(Abuf + (size_t)csr[e + 3] * KP + 160);
        unsigned int p0 = r0[lane], p1 = r1[lane], p2 = r2[lane], p3 = r3[lane];
        unsigned int q0 = 0, q1 = 0, q2 = 0, q3 = 0;
        if (tail) { q0 = r0[64 + lane]; q1 = r1[64 + lane]; q2 = r2[64 + lane]; q3 = r3[64 + lane]; }
        a0 += blo(p0) + blo(p1) + blo(p2) + blo(p3);
        a1 += bhi(p0) + bhi(p1) + bhi(p2) + bhi(p3);
        b0 += blo(q0) + blo(q1) + blo(q2) + blo(q3);
        b1 += bhi(q0) + bhi(q1) + bhi(q2) + bhi(q3);
    }
    for (; e < e1; ++e) {
        const unsigned int* r = (const unsigned int*)(Abuf + (size_t)csr[e] * KP + 160);
        unsigned int p = r[lane];
        unsigned int q = tail ? r[64 + lane] : 0;
        a0 += blo(p); a1 += bhi(p);
        b0 += blo(q); b1 += bhi(q);
    }
    unsigned int* out = (unsigned int*)(Abuf + (size_t)node * KP);
    out[lane] = (unsigned int)bf_bits(a0) | ((unsigned int)bf_bits(a1) << 16);
    if (tail) out[64 + lane] = (unsigned int)bf_bits(b0) | ((unsigned int)bf_bits(b1) << 16);
    if (lane < 5) out[75 + lane] = (lane == 0) ? 0x00003F80u : 0u;
}

// ---------------- fused GEMM + GRU epilogue ----------------
__global__ __launch_bounds__(256, 2)
void gemm_gru(const bf16* __restrict__ Abuf, const bf16* __restrict__ wfrag_l,
              const float* __restrict__ h_in, float* __restrict__ h_out,
              bf16* __restrict__ Abuf_w) {
    __shared__ __align__(16) bf16 As[KS * BM * 32];   // [ks][row][32k]  40 KB
    __shared__ __align__(16) bf16 Bs[NT * 64 * 8];    // [ntile][lane][8] 40 KB
    int tid = threadIdx.x;
    int wave = tid >> 6, lane = tid & 63;
    int mh = wave >> 1, nh = wave & 1;
    int row0 = blockIdx.x * BM;

    {
        const char* gbase = (const char*)(Abuf + (size_t)row0 * KP);
        char* lbase = (char*)As;
#pragma unroll
        for (int it = 0; it < 10; ++it) {
            int c = it * 256 + tid;
            int ks = c >> 8;
            int rem = c & 255;
            int r = rem >> 2, q = rem & 3;
            gld_lds16(gbase + (size_t)r * (KP * 2) + ks * 64 + q * 16,
                      lbase + (size_t)c * 16);
        }
    }
    {
        const char* gb = (const char*)wfrag_l;
        char* lb = (char*)Bs;
#pragma unroll
        for (int it = 0; it < 10; ++it) {
            int c = it * 256 + tid;
            gld_lds16(gb + (size_t)c * 16, lb + (size_t)c * 16);
        }
    }
    __syncthreads();

    f32x4 acc[2][20];
#pragma unroll
    for (int mt = 0; mt < 2; ++mt)
#pragma unroll
        for (int t = 0; t < 20; ++t) acc[mt][t] = (f32x4){0.f, 0.f, 0.f, 0.f};

    int col = lane & 15, q = lane >> 4;
    for (int ks = 0; ks < KS; ++ks) {
        short8 a0 = *(const short8*)(As + ((size_t)(ks * BM + mh * 32 + col) * 32 + q * 8));
        short8 a1 = *(const short8*)(As + ((size_t)(ks * BM + mh * 32 + 16 + col) * 32 + q * 8));
#pragma unroll
        for (int g = 0; g < 5; ++g) {
#pragma unroll
            for (int s = 0; s < 4; ++s) {
                int nt = s * 10 + nh * 5 + g;
                short8 b = *(const short8*)(Bs + ((size_t)(nt * 64 + lane) * 8));
                acc[0][g * 4 + s] = __builtin_amdgcn_mfma_f32_16x16x32_bf16(a0, b, acc[0][g * 4 + s], 0, 0, 0);
                acc[1][g * 4 + s] = __builtin_amdgcn_mfma_f32_16x16x32_bf16(a1, b, acc[1][g * 4 + s], 0, 0, 0);
            }
        }
        __syncthreads();
        if (ks < KS - 1) {
            const char* gb = (const char*)(wfrag_l + (size_t)(ks + 1) * NT * 64 * 8);
            char* lb = (char*)Bs;
#pragma unroll
            for (int it = 0; it < 10; ++it) {
                int c = it * 256 + tid;
                gld_lds16(gb + (size_t)c * 16, lb + (size_t)c * 16);
            }
            __syncthreads();
        }
    }

    int qrow = q * 4;
#pragma unroll
    for (int mt = 0; mt < 2; ++mt) {
#pragma unroll
        for (int g = 0; g < 5; ++g) {
            int f = (nh * 5 + g) * 16 + col;
            if (f < HID) {
                f32x4 ar = acc[mt][g * 4 + 0], az = acc[mt][g * 4 + 1];
                f32x4 an = acc[mt][g * 4 + 2], ah = acc[mt][g * 4 + 3];
#pragma unroll
                for (int v = 0; v < 4; ++v) {
                    int m = row0 + mh * 32 + mt * 16 + qrow + v;
                    if (m < NN) {
                        float r = 1.f / (1.f + __expf(-ar[v]));
                        float z = 1.f / (1.f + __expf(-az[v]));
                        float n = tanhf(an[v] + r * ah[v]);
                        float hp = h_in[(size_t)m * HID + f];
                        float ho = (1.f - z) * n + z * hp;
                        h_out[(size_t)m * HID + f] = ho;
                        Abuf_w[(size_t)m * KP + 160 + f] = __float2bfloat16(ho);
                    }
                }
            }
        }
    }
}

extern "C" void kernel_launch(void* const* d_in, const int* in_sizes, int n_in,
                              void* d_out, int out_size, void* d_ws, size_t ws_size,
                              hipStream_t stream) {
    const float* x      = (const float*)d_in[0];
    const float* weight = (const float*)d_in[1];
    const float* w_ih   = (const float*)d_in[2];
    const float* w_hh   = (const float*)d_in[3];
    const float* b_ih   = (const float*)d_in[4];
    const float* b_hh   = (const float*)d_in[5];
    const int*   ei     = (const int*)d_in[6];
    float* h = (float*)d_out;

    const int nblk = (NN + BM - 1) / BM;          // 1563
    const size_t NNP = (size_t)nblk * BM;
    char* p = (char*)d_ws;
    auto alloc = [&](size_t bytes) { char* r = p; p += (bytes + 255) & ~255ull; return r; };
    int*  off   = (int*)alloc((size_t)(NN + 1) * 4);
    int*  pos   = (int*)alloc((size_t)NN * 4);
    int*  deg   = (int*)alloc((size_t)NN * 4);
    int*  part  = (int*)alloc((size_t)NPART * 4);
    int*  csr   = (int*)alloc((size_t)NE * 4);
    bf16* wfrag = (bf16*)alloc((size_t)NL * KS * NT * 64 * 8 * 2);
    bf16* Abuf  = (bf16*)alloc((NNP + BM) * (size_t)KP * 2);

    hipMemsetAsync(deg, 0, (size_t)NN * 4, stream);
    build_wfrag<<<(NL * KP * NP + 255) / 256, 256, 0, stream>>>(weight, w_ih, w_hh, b_ih, b_hh, wfrag);
    hist_deg<<<(NE + 255) / 256, 256, 0, stream>>>(ei, deg);
    scan_part<<<NPART, 256, 0, stream>>>(deg, part);
    scan_part2<<<1, 128, 0, stream>>>(part, off);
    scan_write<<<NPART, 256, 0, stream>>>(deg, part, off, pos);
    fill_csr<<<(NE + 255) / 256, 256, 0, stream>>>(ei, pos, csr);
    init_h<<<(int)(((size_t)NN * HID + 255) / 256), 256, 0, stream>>>(x, Abuf);

    for (int l = 0; l < NL; ++l) {
        const float* hin = (l == 0) ? x : h;
        aggregate<<<(NN * 64 + 255) / 256, 256, 0, stream>>>(Abuf, off, csr);
        gemm_gru<<<nblk, 256, 0, stream>>>(Abuf, wfrag + (size_t)l * KS * NT * 512,
                                           hin, h, Abuf);
    }
}

// Round 7
// 1303.562 us; speedup vs baseline: 6.6344x; 1.0783x over previous
//
#include <hip/hip_runtime.h>
#include <hip/hip_bf16.h>
#include <cmath>

#define HID 150
#define NN 100000
#define NE 1600000
#define NL 5
#define G3 (3*HID)          // 450
#define KP 320              // padded K: [aggr 0..149 | bias row 150 | pad | h 160..309 | pad]
#define NP 640              // padded N: 4 sections x 160 (r, z, i_n, h_n)
#define KS 10               // k-steps of 32
#define BM 64               // rows per block
#define NPART 98            // ceil(25000 int4 / 256)
#define HSTEPS 20           // half-k-steps (ks x {sec01, sec23})
#define HS_BF (20*64*8)     // bf16 per half-step chunk = 10240 (20 KB)

typedef __hip_bfloat16 bf16;
using short8 = __attribute__((ext_vector_type(8))) short;
using f32x4  = __attribute__((ext_vector_type(4))) float;

static __device__ __forceinline__ unsigned short bf_bits(float v) {
    __hip_bfloat16 h = __float2bfloat16(v);
    return *reinterpret_cast<unsigned short*>(&h);
}

static __device__ __forceinline__ float blo(unsigned int p) {
    return __uint_as_float((p & 0xffffu) << 16);
}
static __device__ __forceinline__ float bhi(unsigned int p) {
    return __uint_as_float(p & 0xffff0000u);
}

static __device__ __forceinline__ void gld_lds16(const void* g, void* l) {
    __builtin_amdgcn_global_load_lds(
        (const __attribute__((address_space(1))) void*)g,
        (__attribute__((address_space(3))) void*)l, 16, 0, 0);
}

// ---------------- build W fragments (per layer, half-step-contiguous B-frag order) ----
// chunk layout: [l][ks][half][tl(20)][lane(64)][8], tl = s2*10 + fgroup
__global__ void build_wfrag(const float* __restrict__ W, const float* __restrict__ w_ih,
                            const float* __restrict__ w_hh, const float* __restrict__ b_ih,
                            const float* __restrict__ b_hh, bf16* __restrict__ wfrag) {
    int idx = blockIdx.x * 256 + threadIdx.x;
    if (idx >= NL * KP * NP) return;
    int j = idx % NP;
    int k = (idx / NP) % KP;
    int l = idx / (NP * KP);
    int sec = j / 160;
    int f = j - sec * 160;
    float v = 0.f;
    if (f < HID) {
        if (k < HID) {
            if (sec < 3) {  // aggr rows: fused = W_l @ w_ih^T
                const float* Wl = W + (size_t)l * HID * HID + (size_t)k * HID;
                const float* wr = w_ih + (size_t)(sec * HID + f) * HID;
                float acc = 0.f;
                for (int t = 0; t < HID; ++t) acc += Wl[t] * wr[t];
                v = acc;
            }
        } else if (k == HID) {  // bias row (A has ones here)
            v = (sec == 0) ? b_ih[f] + b_hh[f]
              : (sec == 1) ? b_ih[HID + f] + b_hh[HID + f]
              : (sec == 2) ? b_ih[2 * HID + f]
                           : b_hh[2 * HID + f];
        } else if (k >= 160 && k < 160 + HID) {  // h rows
            int kk = k - 160;
            if (sec == 0)      v = w_hh[(size_t)f * HID + kk];
            else if (sec == 1) v = w_hh[(size_t)(HID + f) * HID + kk];
            else if (sec == 3) v = w_hh[(size_t)(2 * HID + f) * HID + kk];
        }
    }
    int kstep = k >> 5, kq = (k >> 3) & 3, ki = k & 7;
    int half = sec >> 1, s2 = sec & 1;
    int fgroup = f >> 4, nl = j & 15;
    int tl = s2 * 10 + fgroup;
    int lane = kq * 16 + nl;
    size_t addr = ((((size_t)(l * KS + kstep) * 2 + half) * 20 + tl) * 64 + lane) * 8 + ki;
    wfrag[addr] = __float2bfloat16(v);
}

// ---------------- CSR build ----------------
__global__ void hist_deg(const int* __restrict__ ei, int* __restrict__ deg) {
    int e = blockIdx.x * blockDim.x + threadIdx.x;
    if (e < NE) atomicAdd(&deg[ei[NE + e]], 1);
}

__global__ void scan_part(const int* __restrict__ deg, int* __restrict__ part) {
    int gid = blockIdx.x * 256 + threadIdx.x;     // int4 index
    int4 v = {0, 0, 0, 0};
    if (gid * 4 < NN) v = ((const int4*)deg)[gid];
    int s = v.x + v.y + v.z + v.w;
    __shared__ int red[4];
    for (int d = 32; d; d >>= 1) s += __shfl_down(s, d, 64);
    if ((threadIdx.x & 63) == 0) red[threadIdx.x >> 6] = s;
    __syncthreads();
    if (threadIdx.x == 0) part[blockIdx.x] = red[0] + red[1] + red[2] + red[3];
}

__global__ void scan_part2(int* __restrict__ part, int* __restrict__ off) {
    __shared__ int s[128];
    int t = threadIdx.x;
    int v = (t < NPART) ? part[t] : 0;
    s[t] = v;
    __syncthreads();
    for (int d = 1; d < 128; d <<= 1) {
        int u = (t >= d) ? s[t - d] : 0;
        __syncthreads();
        s[t] += u;
        __syncthreads();
    }
    if (t < NPART) part[t] = s[t] - v;
    if (t == 127) off[NN] = s[127];
}

__global__ void scan_write(const int* __restrict__ deg, const int* __restrict__ part,
                           int* __restrict__ off, int* __restrict__ pos) {
    __shared__ int s[256];
    int t = threadIdx.x;
    int gid = blockIdx.x * 256 + t;
    int4 v = {0, 0, 0, 0};
    if (gid * 4 < NN) v = ((const int4*)deg)[gid];
    int sum = v.x + v.y + v.z + v.w;
    s[t] = sum;
    __syncthreads();
    for (int d = 1; d < 256; d <<= 1) {
        int u = (t >= d) ? s[t - d] : 0;
        __syncthreads();
        s[t] += u;
        __syncthreads();
    }
    int base = part[blockIdx.x] + s[t] - sum;
    if (gid * 4 < NN) {
        int4 o;
        o.x = base;
        o.y = base + v.x;
        o.z = o.y + v.y;
        o.w = o.z + v.z;
        ((int4*)off)[gid] = o;
        ((int4*)pos)[gid] = o;
    }
}

__global__ void fill_csr(const int* __restrict__ ei, int* __restrict__ pos,
                         int* __restrict__ csr) {
    int e = blockIdx.x * blockDim.x + threadIdx.x;
    if (e < NE) {
        int p = atomicAdd(&pos[ei[NE + e]], 1);
        csr[p] = ei[e];
    }
}

// ---------------- x -> Abuf h-region (bf16) ----------------
__global__ void init_h(const float* __restrict__ x, bf16* __restrict__ Abuf) {
    size_t i = (size_t)blockIdx.x * 256 + threadIdx.x;
    if (i >= (size_t)NN * HID) return;
    int m = (int)(i / HID), f = (int)(i - (size_t)m * HID);
    Abuf[(size_t)m * KP + 160 + f] = __float2bfloat16(x[i]);
}

// ---------------- aggregate: wave per node, 4-deep pipelined gather ----------------
__global__ void aggregate(bf16* __restrict__ Abuf, const int* __restrict__ off,
                          const int* __restrict__ csr) {
    int node = (blockIdx.x * blockDim.x + threadIdx.x) >> 6;
    int lane = threadIdx.x & 63;
    if (node >= NN) return;
    int e0 = off[node], e1 = off[node + 1];
    float a0 = 0.f, a1 = 0.f, b0 = 0.f, b1 = 0.f;
    bool tail = lane < 11;   // uints 64..74 cover features 128..149
    int e = e0;
    for (; e + 4 <= e1; e += 4) {
        const unsigned int* r0 = (const unsigned int*)(Abuf + (size_t)csr[e]     * KP + 160);
        const unsigned int* r1 = (const unsigned int*)(Abuf + (size_t)csr[e + 1] * KP + 160);
        const unsigned int* r2 = (const unsigned int*)(Abuf + (size_t)csr[e + 2] * KP + 160);
        const unsigned int* r3 = (const unsigned int*)(Abuf + (size_t)csr[e + 3] * KP + 160);
        unsigned int p0 = r0[lane], p1 = r1[lane], p2 = r2[lane], p3 = r3[lane];
        unsigned int q0 = 0, q1 = 0, q2 = 0, q3 = 0;
        if (tail) { q0 = r0[64 + lane]; q1 = r1[64 + lane]; q2 = r2[64 + lane]; q3 = r3[64 + lane]; }
        a0 += blo(p0) + blo(p1) + blo(p2) + blo(p3);
        a1 += bhi(p0) + bhi(p1) + bhi(p2) + bhi(p3);
        b0 += blo(q0) + blo(q1) + blo(q2) + blo(q3);
        b1 += bhi(q0) + bhi(q1) + bhi(q2) + bhi(q3);
    }
    for (; e < e1; ++e) {
        const unsigned int* r = (const unsigned int*)(Abuf + (size_t)csr[e] * KP + 160);
        unsigned int p = r[lane];
        unsigned int q = tail ? r[64 + lane] : 0;
        a0 += blo(p); a1 += bhi(p);
        b0 += blo(q); b1 += bhi(q);
    }
    unsigned int* out = (unsigned int*)(Abuf + (size_t)node * KP);
    out[lane] = (unsigned int)bf_bits(a0) | ((unsigned int)bf_bits(a1) << 16);
    if (tail) out[64 + lane] = (unsigned int)bf_bits(b0) | ((unsigned int)bf_bits(b1) << 16);
    if (lane < 5) out[75 + lane] = (lane == 0) ? 0x00003F80u : 0u;
}

// ---------------- fused GEMM + GRU epilogue, ping-pong B staging ----------------
// 4 waves: mh = wave>>1 (32-row half), nh = wave&1 (feature half)
// K-loop over 20 half-steps; B for hs+1 staged into other buffer BEFORE MFMA of hs.
__global__ __launch_bounds__(256, 2)
void gemm_gru(const bf16* __restrict__ Abuf, const bf16* __restrict__ wfrag_l,
              float* __restrict__ h_out, bf16* __restrict__ Abuf_w, int last) {
    __shared__ __align__(16) bf16 As[KS * BM * 32];   // 40 KB, static all K
    __shared__ __align__(16) bf16 Bs[2][HS_BF];       // 2 x 20 KB ping-pong
    int tid = threadIdx.x;
    int wave = tid >> 6, lane = tid & 63;
    int mh = wave >> 1, nh = wave & 1;
    int row0 = blockIdx.x * BM;

    // stage all of A (2560 x 16 B) + B half-step 0 (1280 x 16 B)
    {
        const char* gbase = (const char*)(Abuf + (size_t)row0 * KP);
        char* lbase = (char*)As;
#pragma unroll
        for (int it = 0; it < 10; ++it) {
            int c = it * 256 + tid;
            int ks = c >> 8;
            int rem = c & 255;
            int r = rem >> 2, qq = rem & 3;
            gld_lds16(gbase + (size_t)r * (KP * 2) + ks * 64 + qq * 16,
                      lbase + (size_t)c * 16);
        }
        const char* gb = (const char*)wfrag_l;
        char* lb = (char*)Bs[0];
#pragma unroll
        for (int it = 0; it < 5; ++it) {
            int c = it * 256 + tid;
            gld_lds16(gb + (size_t)c * 16, lb + (size_t)c * 16);
        }
    }
    __syncthreads();

    f32x4 acc[2][20];
#pragma unroll
    for (int mt = 0; mt < 2; ++mt)
#pragma unroll
        for (int t = 0; t < 20; ++t) acc[mt][t] = (f32x4){0.f, 0.f, 0.f, 0.f};

    int col = lane & 15, q = lane >> 4;
    short8 a0, a1;
    for (int hs = 0; hs < HSTEPS; ++hs) {
        int cur = hs & 1;
        // issue staging of next half-step into the other buffer (overlaps MFMA below)
        if (hs < HSTEPS - 1) {
            const char* gb = (const char*)(wfrag_l + (size_t)(hs + 1) * HS_BF);
            char* lb = (char*)Bs[1 - cur];
#pragma unroll
            for (int it = 0; it < 5; ++it) {
                int c = it * 256 + tid;
                gld_lds16(gb + (size_t)c * 16, lb + (size_t)c * 16);
            }
        }
        int ks = hs >> 1, half = hs & 1;
        if (half == 0) {
            a0 = *(const short8*)(As + ((size_t)(ks * BM + mh * 32 + col) * 32 + q * 8));
            a1 = *(const short8*)(As + ((size_t)(ks * BM + mh * 32 + 16 + col) * 32 + q * 8));
        }
#pragma unroll
        for (int g = 0; g < 5; ++g) {
#pragma unroll
            for (int s2 = 0; s2 < 2; ++s2) {
                int tl = s2 * 10 + nh * 5 + g;
                short8 b = *(const short8*)(Bs[cur] + ((size_t)(tl * 64 + lane) * 8));
                int t = g * 4 + half * 2 + s2;
                acc[0][t] = __builtin_amdgcn_mfma_f32_16x16x32_bf16(a0, b, acc[0][t], 0, 0, 0);
                acc[1][t] = __builtin_amdgcn_mfma_f32_16x16x32_bf16(a1, b, acc[1][t], 0, 0, 0);
            }
        }
        __syncthreads();   // waves done with Bs[cur]; staging into Bs[1-cur] drained
    }

    // epilogue: C layout col=lane&15, row=(lane>>4)*4+reg ; hp comes from As (bf16 h rows)
    int qrow = q * 4;
    bf16* Cs = &Bs[0][0];   // reuse as [64][160] bf16 staging for coalesced writes
#pragma unroll
    for (int mt = 0; mt < 2; ++mt) {
#pragma unroll
        for (int g = 0; g < 5; ++g) {
            int f = (nh * 5 + g) * 16 + col;
            if (f < HID) {
                f32x4 ar = acc[mt][g * 4 + 0], az = acc[mt][g * 4 + 1];
                f32x4 an = acc[mt][g * 4 + 2], ah = acc[mt][g * 4 + 3];
                int kh = 160 + f, ksh = kh >> 5, koff = kh & 31;
#pragma unroll
                for (int v = 0; v < 4; ++v) {
                    int rl = mh * 32 + mt * 16 + qrow + v;
                    float hp = __bfloat162float(As[((size_t)(ksh * BM) + rl) * 32 + koff]);
                    float r = 1.f / (1.f + __expf(-ar[v]));
                    float z = 1.f / (1.f + __expf(-az[v]));
                    float n = tanhf(an[v] + r * ah[v]);
                    float ho = (1.f - z) * n + z * hp;
                    if (last) {
                        int m = row0 + rl;
                        if (m < NN) h_out[(size_t)m * HID + f] = ho;
                    } else {
                        Cs[rl * 160 + f] = __float2bfloat16(ho);
                    }
                }
            }
        }
    }
    if (!last) {
        __syncthreads();
        // coalesced copy Cs -> Abuf h-region: 64 rows x 75 dwords (150 bf16)
        const unsigned int* src = (const unsigned int*)Cs;
        for (int i = tid; i < 64 * 75; i += 256) {
            int r = i / 75, dw = i - r * 75;
            ((unsigned int*)(Abuf_w + (size_t)(row0 + r) * KP + 160))[dw] =
                src[r * 80 + dw];
        }
    }
}

extern "C" void kernel_launch(void* const* d_in, const int* in_sizes, int n_in,
                              void* d_out, int out_size, void* d_ws, size_t ws_size,
                              hipStream_t stream) {
    const float* x      = (const float*)d_in[0];
    const float* weight = (const float*)d_in[1];
    const float* w_ih   = (const float*)d_in[2];
    const float* w_hh   = (const float*)d_in[3];
    const float* b_ih   = (const float*)d_in[4];
    const float* b_hh   = (const float*)d_in[5];
    const int*   ei     = (const int*)d_in[6];
    float* h = (float*)d_out;

    const int nblk = (NN + BM - 1) / BM;          // 1563
    const size_t NNP = (size_t)nblk * BM;
    char* p = (char*)d_ws;
    auto alloc = [&](size_t bytes) { char* r = p; p += (bytes + 255) & ~255ull; return r; };
    int*  off   = (int*)alloc((size_t)(NN + 1) * 4);
    int*  pos   = (int*)alloc((size_t)NN * 4);
    int*  deg   = (int*)alloc((size_t)NN * 4);
    int*  part  = (int*)alloc((size_t)NPART * 4);
    int*  csr   = (int*)alloc((size_t)NE * 4);
    bf16* wfrag = (bf16*)alloc((size_t)NL * KS * 2 * HS_BF * 2);
    bf16* Abuf  = (bf16*)alloc((NNP + BM) * (size_t)KP * 2);

    hipMemsetAsync(deg, 0, (size_t)NN * 4, stream);
    build_wfrag<<<(NL * KP * NP + 255) / 256, 256, 0, stream>>>(weight, w_ih, w_hh, b_ih, b_hh, wfrag);
    hist_deg<<<(NE + 255) / 256, 256, 0, stream>>>(ei, deg);
    scan_part<<<NPART, 256, 0, stream>>>(deg, part);
    scan_part2<<<1, 128, 0, stream>>>(part, off);
    scan_write<<<NPART, 256, 0, stream>>>(deg, part, off, pos);
    fill_csr<<<(NE + 255) / 256, 256, 0, stream>>>(ei, pos, csr);
    init_h<<<(int)(((size_t)NN * HID + 255) / 256), 256, 0, stream>>>(x, Abuf);

    for (int l = 0; l < NL; ++l) {
        aggregate<<<(NN * 64 + 255) / 256, 256, 0, stream>>>(Abuf, off, csr);
        gemm_gru<<<nblk, 256, 0, stream>>>(Abuf, wfrag + (size_t)l * KS * 2 * HS_BF,
                                           h, Abuf, (l == NL - 1) ? 1 : 0);
    }
}